// Round 2
// baseline (2043.136 us; speedup 1.0000x reference)
//
#include <hip/hip_runtime.h>
#include <cstdint>
#include <cstddef>

#define BB 2
#define HH 16
#define SS 2048
#define DD 1024
#define DA 64
#define TOPK 32
#define ROWS 4   // q-rows per workgroup (1 per wave)

// ---------------- Projection GEMM: O = X @ W^T (OpenBLAS-sgemm-faithful) ----
// Per output element: strictly sequential FMA over k ascending, kc=384 panels
// combined as ((P0)+P1)+P2.  Tile 64x64, micro 4x4, 4 WGs/CU.
// Both projections fused into one launch via blockIdx.z.
// Output layout (both Q and K): O[((b*16+h)*2048+s)*64+da]
__global__ __launch_bounds__(256, 4) void proj_kernel(const float* __restrict__ X0,
                                                      const float* __restrict__ W0,
                                                      float* __restrict__ O0,
                                                      const float* __restrict__ X1,
                                                      const float* __restrict__ W1,
                                                      float* __restrict__ O1) {
  const float* __restrict__ X = blockIdx.z ? X1 : X0;
  const float* __restrict__ W = blockIdx.z ? W1 : W0;
  float* __restrict__ O       = blockIdx.z ? O1 : O0;

  __shared__ float Ast[16][64];
  __shared__ float Bst[16][64];
  const int tid = threadIdx.x;
  const int tx = tid & 15, ty = tid >> 4;
  const int m0 = blockIdx.y * 64, n0 = blockIdx.x * 64;

  float res[4][4], acc[4][4];
#pragma unroll
  for (int i = 0; i < 4; ++i)
#pragma unroll
    for (int j = 0; j < 4; ++j) { res[i][j] = 0.f; acc[i][j] = 0.f; }

  const int srow = tid >> 2, skg = tid & 3;   // staging: one float4 per thread
  for (int k0 = 0; k0 < 1024; k0 += 16) {
    if (k0 == 384 || k0 == 768) {   // OpenBLAS kc-panel boundary
#pragma unroll
      for (int i = 0; i < 4; ++i)
#pragma unroll
        for (int j = 0; j < 4; ++j) { res[i][j] = __fadd_rn(res[i][j], acc[i][j]); acc[i][j] = 0.f; }
    }
    {
      const float4 va = *(const float4*)(X + (size_t)(m0 + srow) * 1024 + k0 + skg * 4);
      Ast[skg * 4 + 0][srow] = va.x; Ast[skg * 4 + 1][srow] = va.y;
      Ast[skg * 4 + 2][srow] = va.z; Ast[skg * 4 + 3][srow] = va.w;
      const float4 vb = *(const float4*)(W + (size_t)(n0 + srow) * 1024 + k0 + skg * 4);
      Bst[skg * 4 + 0][srow] = vb.x; Bst[skg * 4 + 1][srow] = vb.y;
      Bst[skg * 4 + 2][srow] = vb.z; Bst[skg * 4 + 3][srow] = vb.w;
    }
    __syncthreads();
#pragma unroll
    for (int k = 0; k < 16; ++k) {
      float av[4], bv[4];
#pragma unroll
      for (int i = 0; i < 4; ++i) av[i] = Ast[k][ty * 4 + i];
#pragma unroll
      for (int j = 0; j < 4; ++j) bv[j] = Bst[k][tx * 4 + j];
#pragma unroll
      for (int i = 0; i < 4; ++i)
#pragma unroll
        for (int j = 0; j < 4; ++j) acc[i][j] = fmaf(av[i], bv[j], acc[i][j]);
    }
    __syncthreads();
  }

#pragma unroll
  for (int i = 0; i < 4; ++i) {
    const int m = m0 + ty * 4 + i;
    const int b = m >> 11, s = m & 2047;
#pragma unroll
    for (int j = 0; j < 4; ++j) {
      const int n = n0 + tx * 4 + j;
      const int h = n >> 6, da = n & 63;
      O[(((size_t)(b * 16 + h) * 2048 + s) * 64 + da)] = __fadd_rn(res[i][j], acc[i][j]);
    }
  }
}

// ---------------- Fused topk-attention (np.einsum-faithful f32 scores) ------
// Bit-identical per-(row,key) chain (SSE 4-lane, no FMA, groups of 16
// ascending, 4-blocks descending, (a0+a1)+(a2+a3), *0.125).
// WG = 256 threads (4 waves) per (bh, 4 q-rows).  LDS exactly 32768 B.
//
// Round-2 changes (both latency-only; FLOP sequence untouched):
//  * XCD-chunked bijective block swizzle: all 512 row-blocks of one (b,h)
//    run on one XCD -> its 512KB K panel (and V panel for the PV gather)
//    stays L2-resident instead of thrashing 32 panels through every L2
//    and falling back to ~600cy Infinity-Cache reads.
//  * Explicit 4-buffer K prefetch: each 4xfloat4 K group is issued >=256
//    MAC instructions before its first use (cross-c for groups 0/1), so
//    load latency hides under compute instead of stalling every 128 MACs
//    (VGPR_Count was 48 -> compiler had only one group in flight).
__global__ __launch_bounds__(256, 4) void attn_kernel(const float* __restrict__ Qp,
                                                      const float* __restrict__ Kp,
                                                      const float* __restrict__ V,
                                                      float* __restrict__ out) {
  __shared__ float Srow[ROWS * 2048];   // 32 KB score block (+aliased lists)

  const int tid = threadIdx.x;
  const int w = tid >> 6, l = tid & 63;
  // bijective XCD-chunk swizzle (nwg = 16384, divisible by 8 XCDs)
  const int nwg = BB * HH * (SS / ROWS);
  const int bidx = (int)blockIdx.x;
  const int swz = (bidx & 7) * (nwg >> 3) + (bidx >> 3);
  const int bh = swz >> 9;
  const int rb = swz & 511;
  const int b = bh >> 4, h = bh & 15;
  const int r0 = rb * ROWS;

  const float* Kh = Kp + (size_t)bh * SS * DA;             // [2048][64]

#define LOAD_G(buf, kbase, g)                                             \
  { _Pragma("unroll")                                                     \
    for (int i_ = 0; i_ < 4; ++i_) buf[i_] = (kbase)[(g) * 4 + i_]; }

// Exact original arithmetic: rows ascending, 4-blocks DESCENDING, per-sse-lane
// accumulation with separate __fmul_rn/__fadd_rn.  Only load timing differs.
#define COMPUTE_G(buf, g)                                                 \
  { _Pragma("unroll")                                                     \
    for (int r_ = 0; r_ < ROWS; ++r_) {                                   \
      const float4* qp4_ = (const float4*)(Qp + ((size_t)bh * SS + r0 + r_) * DA); \
      float4 q4_[4];                                                      \
      _Pragma("unroll")                                                   \
      for (int i_ = 0; i_ < 4; ++i_) q4_[i_] = qp4_[(g) * 4 + i_];        \
      _Pragma("unroll")                                                   \
      for (int blk_ = 3; blk_ >= 0; --blk_) {                             \
        acc[r_][0] = __fadd_rn(acc[r_][0], __fmul_rn(q4_[blk_].x, buf[blk_].x)); \
        acc[r_][1] = __fadd_rn(acc[r_][1], __fmul_rn(q4_[blk_].y, buf[blk_].y)); \
        acc[r_][2] = __fadd_rn(acc[r_][2], __fmul_rn(q4_[blk_].z, buf[blk_].z)); \
        acc[r_][3] = __fadd_rn(acc[r_][3], __fmul_rn(q4_[blk_].w, buf[blk_].w)); \
      } } }

  // ----- score phase: each thread handles keys tid + 256*c, c = 0..7 --------
  float4 b0[4], b1[4], b2[4], b3[4];
  {
    const float4* kp40 = (const float4*)(Kh + (size_t)tid * DA);
    LOAD_G(b0, kp40, 0);
    LOAD_G(b1, kp40, 1);
  }
#pragma unroll 1
  for (int c = 0; c < 8; ++c) {
    const int key = tid + c * 256;
    const float4* kp4  = (const float4*)(Kh + (size_t)key * DA);
    const float4* kp4n = (const float4*)(Kh + (size_t)(tid + ((c + 1) & 7) * 256) * DA);

    float acc[ROWS][4];                 // [row][sse-lane], static-indexed
#pragma unroll
    for (int r = 0; r < ROWS; ++r)
#pragma unroll
      for (int j = 0; j < 4; ++j) acc[r][j] = 0.f;

    LOAD_G(b2, kp4, 2);                 // this-c group 2 in flight
    COMPUTE_G(b0, 0);                   // group 0 (loaded last iteration)
    LOAD_G(b3, kp4, 3);                 // this-c group 3 in flight
    COMPUTE_G(b1, 1);                   // group 1 (loaded last iteration)
    LOAD_G(b0, kp4n, 0);                // next-c group 0 in flight
    COMPUTE_G(b2, 2);
    LOAD_G(b1, kp4n, 1);                // next-c group 1 in flight
    COMPUTE_G(b3, 3);

#pragma unroll
    for (int r = 0; r < ROWS; ++r) {
      const float s = __fadd_rn(__fadd_rn(acc[r][0], acc[r][1]),
                                __fadd_rn(acc[r][2], acc[r][3]));
      Srow[r * 2048 + key] = s * 0.125f;
    }
  }
#undef LOAD_G
#undef COMPUTE_G
  __syncthreads();

  const float* Vh = V + (size_t)b * SS * DD + h * DA;
  float* outh = out + ((size_t)(b * SS + r0 + w)) * DD + h * DA;

  // ----- per-wave: one row (r = w): exact top-32, softmax, sparse PV --------
  {
    const int r = w;
    float sv[32];
#pragma unroll
    for (int i = 0; i < 32; ++i) sv[i] = Srow[r * 2048 + 64 * i + l];
    // From here on, this wave's Srow slice is dead: reuse the first 128
    // floats of it as the survivor (weight,key) lists.
    float* wl = &Srow[r * 2048];        // [0..63]  survivor weights
    float* kl = &Srow[r * 2048 + 64];   // [64..127] survivor keys (bit-punned)

    float mx = sv[0], mn = sv[0];
#pragma unroll
    for (int i = 1; i < 32; ++i) { mx = fmaxf(mx, sv[i]); mn = fminf(mn, sv[i]); }
#pragma unroll
    for (int off = 32; off >= 1; off >>= 1) {
      mx = fmaxf(mx, __shfl_xor(mx, off));
      mn = fminf(mn, __shfl_xor(mn, off));
    }

    // bisection for the exact 32nd-largest score value.
    float lo = mn, hi = mx + 1.0f;
    float cutoff = mn;
    for (int it = 0; ; ++it) {
      const float mid = 0.5f * (lo + hi);
      if (it >= 64 || !(mid > lo && mid < hi)) { cutoff = lo; break; }
      int c = 0;
#pragma unroll
      for (int i = 0; i < 32; ++i)
        c += (int)__popcll(__ballot(sv[i] >= mid));
      if (c == TOPK) {
        float cm = 3.0e38f;
#pragma unroll
        for (int i = 0; i < 32; ++i) if (sv[i] >= mid) cm = fminf(cm, sv[i]);
#pragma unroll
        for (int off = 32; off >= 1; off >>= 1) cm = fminf(cm, __shfl_xor(cm, off));
        cutoff = cm;
        break;
      }
      if (c > TOPK) lo = mid; else hi = mid;
    }

    // weights on kept entries (ties at cutoff kept, matching scores>=cutoff)
    float wv[32];
    float dpart = 0.f;
    int ckept = 0;
#pragma unroll
    for (int i = 0; i < 32; ++i) {
      const bool keep = (sv[i] >= cutoff);
      ckept += (int)__popcll(__ballot(keep));
      const float e = keep ? __expf(sv[i] - mx) : 0.f;
      wv[i] = e;
      dpart += e;
    }
    float denom = dpart;
#pragma unroll
    for (int off = 32; off >= 1; off >>= 1) denom += __shfl_xor(denom, off);
    const float inv_denom = 1.0f / denom;

    float e = 0.f;
    if (ckept <= 64) {
      // ballot compaction of survivors into the aliased LDS lists (ascending k)
      int base = 0;
#pragma unroll
      for (int i = 0; i < 32; ++i) {
        const unsigned long long mball = __ballot(wv[i] > 0.f);
        if (wv[i] > 0.f) {
          const int pos = base + (int)__popcll(mball & ((1ull << l) - 1ull));
          wl[pos] = wv[i];
          kl[pos] = __int_as_float(64 * i + l);
        }
        base += (int)__popcll(mball);
      }
      asm volatile("s_waitcnt lgkmcnt(0)" ::: "memory");
      // PV gather, batched x8: 8 independent V loads in flight per batch.
      // fma chain order (ascending survivor index) preserved bit-identically.
      int i = 0;
      for (; i + 8 <= ckept; i += 8) {
        float ww[8]; int kk[8];
#pragma unroll
        for (int u = 0; u < 8; ++u) { ww[u] = wl[i + u]; kk[u] = __float_as_int(kl[i + u]); }
        float vv[8];
#pragma unroll
        for (int u = 0; u < 8; ++u) vv[u] = Vh[(size_t)kk[u] * DD + l];
#pragma unroll
        for (int u = 0; u < 8; ++u) e = fmaf(ww[u], vv[u], e);
      }
      for (; i < ckept; ++i) {
        const float ww = wl[i];
        const int kk = __float_as_int(kl[i]);
        e = fmaf(ww, Vh[(size_t)kk * DD + l], e);
      }
    } else {
      // pathological-tie fallback: dense accumulation (own row only)
#pragma unroll
      for (int i = 0; i < 32; ++i) Srow[r * 2048 + 64 * i + l] = wv[i];
      asm volatile("s_waitcnt lgkmcnt(0)" ::: "memory");
      for (int k = 0; k < 2048; ++k) {
        const float ww = Srow[r * 2048 + k];
        if (ww > 0.f) e = fmaf(ww, Vh[(size_t)k * DD + l], e);
      }
    }
    outh[l] = e * inv_denom;
  }
}

extern "C" void kernel_launch(void* const* d_in, const int* in_sizes, int n_in,
                              void* d_out, int out_size, void* d_ws, size_t ws_size,
                              hipStream_t stream) {
  const float* query = (const float*)d_in[0];
  const float* key   = (const float*)d_in[1];
  const float* value = (const float*)d_in[2];
  const float* Wq    = (const float*)d_in[3];
  const float* Wk    = (const float*)d_in[4];
  float* out = (float*)d_out;

  float* Qp = (float*)d_ws;                                  // 16.8 MB
  float* Kp = Qp + (size_t)BB * HH * SS * DA;                // 16.8 MB

  proj_kernel<<<dim3(16, 64, 2), 256, 0, stream>>>(query, Wq, Qp, key, Wk, Kp);
  attn_kernel<<<dim3(BB * HH * (SS / ROWS)), 256, 0, stream>>>(Qp, Kp, value, out);
}

// Round 3
// 1480.192 us; speedup vs baseline: 1.3803x; 1.3803x over previous
//
#include <hip/hip_runtime.h>
#include <cstdint>
#include <cstddef>

#define BB 2
#define HH 16
#define SS 2048
#define DD 1024
#define DA 64
#define TOPK 32
#define ROWS 4   // q-rows per workgroup (1 per wave)

// ---------------- Projection GEMM: O = X @ W^T (OpenBLAS-sgemm-faithful) ----
// Per output element: strictly sequential FMA over k ascending, kc=384 panels
// combined as ((P0)+P1)+P2.  Tile 64x64, micro 4x4, 4 WGs/CU.
// Both projections fused into one launch via blockIdx.z.
// Output layout (both Q and K): O[((b*16+h)*2048+s)*64+da]
__global__ __launch_bounds__(256, 4) void proj_kernel(const float* __restrict__ X0,
                                                      const float* __restrict__ W0,
                                                      float* __restrict__ O0,
                                                      const float* __restrict__ X1,
                                                      const float* __restrict__ W1,
                                                      float* __restrict__ O1) {
  const float* __restrict__ X = blockIdx.z ? X1 : X0;
  const float* __restrict__ W = blockIdx.z ? W1 : W0;
  float* __restrict__ O       = blockIdx.z ? O1 : O0;

  __shared__ float Ast[16][64];
  __shared__ float Bst[16][64];
  const int tid = threadIdx.x;
  const int tx = tid & 15, ty = tid >> 4;
  const int m0 = blockIdx.y * 64, n0 = blockIdx.x * 64;

  float res[4][4], acc[4][4];
#pragma unroll
  for (int i = 0; i < 4; ++i)
#pragma unroll
    for (int j = 0; j < 4; ++j) { res[i][j] = 0.f; acc[i][j] = 0.f; }

  const int srow = tid >> 2, skg = tid & 3;   // staging: one float4 per thread
  for (int k0 = 0; k0 < 1024; k0 += 16) {
    if (k0 == 384 || k0 == 768) {   // OpenBLAS kc-panel boundary
#pragma unroll
      for (int i = 0; i < 4; ++i)
#pragma unroll
        for (int j = 0; j < 4; ++j) { res[i][j] = __fadd_rn(res[i][j], acc[i][j]); acc[i][j] = 0.f; }
    }
    {
      const float4 va = *(const float4*)(X + (size_t)(m0 + srow) * 1024 + k0 + skg * 4);
      Ast[skg * 4 + 0][srow] = va.x; Ast[skg * 4 + 1][srow] = va.y;
      Ast[skg * 4 + 2][srow] = va.z; Ast[skg * 4 + 3][srow] = va.w;
      const float4 vb = *(const float4*)(W + (size_t)(n0 + srow) * 1024 + k0 + skg * 4);
      Bst[skg * 4 + 0][srow] = vb.x; Bst[skg * 4 + 1][srow] = vb.y;
      Bst[skg * 4 + 2][srow] = vb.z; Bst[skg * 4 + 3][srow] = vb.w;
    }
    __syncthreads();
#pragma unroll
    for (int k = 0; k < 16; ++k) {
      float av[4], bv[4];
#pragma unroll
      for (int i = 0; i < 4; ++i) av[i] = Ast[k][ty * 4 + i];
#pragma unroll
      for (int j = 0; j < 4; ++j) bv[j] = Bst[k][tx * 4 + j];
#pragma unroll
      for (int i = 0; i < 4; ++i)
#pragma unroll
        for (int j = 0; j < 4; ++j) acc[i][j] = fmaf(av[i], bv[j], acc[i][j]);
    }
    __syncthreads();
  }

#pragma unroll
  for (int i = 0; i < 4; ++i) {
    const int m = m0 + ty * 4 + i;
    const int b = m >> 11, s = m & 2047;
#pragma unroll
    for (int j = 0; j < 4; ++j) {
      const int n = n0 + tx * 4 + j;
      const int h = n >> 6, da = n & 63;
      O[(((size_t)(b * 16 + h) * 2048 + s) * 64 + da)] = __fadd_rn(res[i][j], acc[i][j]);
    }
  }
}

// ---------------- Fused topk-attention (np.einsum-faithful f32 scores) ------
// Bit-identical per-(row,key) chain (SSE 4-lane, no FMA, groups of 16
// ascending, 4-blocks descending, (a0+a1)+(a2+a3), *0.125).
// WG = 256 threads (4 waves) per (bh, 4 q-rows).  LDS exactly 32768 B.
//
// Round-3 fix: round-2's 4-buffer K prefetch was correct in structure but the
// allocator kept chasing its default 8-waves/EU target (64 VGPRs) and spilled
// the buffers -> 3.1 GB of scratch writes, 2x regression.  Occupancy here is
// LDS-bound at 4-5 WGs/CU (= 4-5 waves/EU), so amdgpu_waves_per_eu(2,4) caps
// the occupancy target at what LDS allows anyway and frees a 128-256 VGPR
// budget: prefetch buffers stay in registers, zero scratch, nothing lost.
__global__ __launch_bounds__(256)
__attribute__((amdgpu_waves_per_eu(2, 4)))
void attn_kernel(const float* __restrict__ Qp,
                 const float* __restrict__ Kp,
                 const float* __restrict__ V,
                 float* __restrict__ out) {
  __shared__ float Srow[ROWS * 2048];   // 32 KB score block (+aliased lists)

  const int tid = threadIdx.x;
  const int w = tid >> 6, l = tid & 63;
  // bijective XCD-chunk swizzle (nwg = 16384, divisible by 8 XCDs)
  const int nwg = BB * HH * (SS / ROWS);
  const int bidx = (int)blockIdx.x;
  const int swz = (bidx & 7) * (nwg >> 3) + (bidx >> 3);
  const int bh = swz >> 9;
  const int rb = swz & 511;
  const int b = bh >> 4, h = bh & 15;
  const int r0 = rb * ROWS;

  const float* Kh = Kp + (size_t)bh * SS * DA;             // [2048][64]

#define LOAD_G(buf, kbase, g)                                             \
  { _Pragma("unroll")                                                     \
    for (int i_ = 0; i_ < 4; ++i_) buf[i_] = (kbase)[(g) * 4 + i_]; }

// Exact original arithmetic: rows ascending, 4-blocks DESCENDING, per-sse-lane
// accumulation with separate __fmul_rn/__fadd_rn.  Only load timing differs.
#define COMPUTE_G(buf, g)                                                 \
  { _Pragma("unroll")                                                     \
    for (int r_ = 0; r_ < ROWS; ++r_) {                                   \
      const float4* qp4_ = (const float4*)(Qp + ((size_t)bh * SS + r0 + r_) * DA); \
      float4 q4_[4];                                                      \
      _Pragma("unroll")                                                   \
      for (int i_ = 0; i_ < 4; ++i_) q4_[i_] = qp4_[(g) * 4 + i_];        \
      _Pragma("unroll")                                                   \
      for (int blk_ = 3; blk_ >= 0; --blk_) {                             \
        acc[r_][0] = __fadd_rn(acc[r_][0], __fmul_rn(q4_[blk_].x, buf[blk_].x)); \
        acc[r_][1] = __fadd_rn(acc[r_][1], __fmul_rn(q4_[blk_].y, buf[blk_].y)); \
        acc[r_][2] = __fadd_rn(acc[r_][2], __fmul_rn(q4_[blk_].z, buf[blk_].z)); \
        acc[r_][3] = __fadd_rn(acc[r_][3], __fmul_rn(q4_[blk_].w, buf[blk_].w)); \
      } } }

  // ----- score phase: each thread handles keys tid + 256*c, c = 0..7 --------
  float4 b0[4], b1[4], b2[4], b3[4];
  {
    const float4* kp40 = (const float4*)(Kh + (size_t)tid * DA);
    LOAD_G(b0, kp40, 0);
    LOAD_G(b1, kp40, 1);
  }
#pragma unroll 1
  for (int c = 0; c < 8; ++c) {
    const int key = tid + c * 256;
    const float4* kp4  = (const float4*)(Kh + (size_t)key * DA);
    const float4* kp4n = (const float4*)(Kh + (size_t)(tid + ((c + 1) & 7) * 256) * DA);

    float acc[ROWS][4];                 // [row][sse-lane], static-indexed
#pragma unroll
    for (int r = 0; r < ROWS; ++r)
#pragma unroll
      for (int j = 0; j < 4; ++j) acc[r][j] = 0.f;

    LOAD_G(b2, kp4, 2);                 // this-c group 2 in flight
    COMPUTE_G(b0, 0);                   // group 0 (loaded last iteration)
    LOAD_G(b3, kp4, 3);                 // this-c group 3 in flight
    COMPUTE_G(b1, 1);                   // group 1 (loaded last iteration)
    LOAD_G(b0, kp4n, 0);                // next-c group 0 in flight
    COMPUTE_G(b2, 2);
    LOAD_G(b1, kp4n, 1);                // next-c group 1 in flight
    COMPUTE_G(b3, 3);

#pragma unroll
    for (int r = 0; r < ROWS; ++r) {
      const float s = __fadd_rn(__fadd_rn(acc[r][0], acc[r][1]),
                                __fadd_rn(acc[r][2], acc[r][3]));
      Srow[r * 2048 + key] = s * 0.125f;
    }
  }
#undef LOAD_G
#undef COMPUTE_G
  __syncthreads();

  const float* Vh = V + (size_t)b * SS * DD + h * DA;
  float* outh = out + ((size_t)(b * SS + r0 + w)) * DD + h * DA;

  // ----- per-wave: one row (r = w): exact top-32, softmax, sparse PV --------
  {
    const int r = w;
    float sv[32];
#pragma unroll
    for (int i = 0; i < 32; ++i) sv[i] = Srow[r * 2048 + 64 * i + l];
    // From here on, this wave's Srow slice is dead: reuse the first 128
    // floats of it as the survivor (weight,key) lists.
    float* wl = &Srow[r * 2048];        // [0..63]  survivor weights
    float* kl = &Srow[r * 2048 + 64];   // [64..127] survivor keys (bit-punned)

    float mx = sv[0], mn = sv[0];
#pragma unroll
    for (int i = 1; i < 32; ++i) { mx = fmaxf(mx, sv[i]); mn = fminf(mn, sv[i]); }
#pragma unroll
    for (int off = 32; off >= 1; off >>= 1) {
      mx = fmaxf(mx, __shfl_xor(mx, off));
      mn = fminf(mn, __shfl_xor(mn, off));
    }

    // bisection for the exact 32nd-largest score value.
    float lo = mn, hi = mx + 1.0f;
    float cutoff = mn;
    for (int it = 0; ; ++it) {
      const float mid = 0.5f * (lo + hi);
      if (it >= 64 || !(mid > lo && mid < hi)) { cutoff = lo; break; }
      int c = 0;
#pragma unroll
      for (int i = 0; i < 32; ++i)
        c += (int)__popcll(__ballot(sv[i] >= mid));
      if (c == TOPK) {
        float cm = 3.0e38f;
#pragma unroll
        for (int i = 0; i < 32; ++i) if (sv[i] >= mid) cm = fminf(cm, sv[i]);
#pragma unroll
        for (int off = 32; off >= 1; off >>= 1) cm = fminf(cm, __shfl_xor(cm, off));
        cutoff = cm;
        break;
      }
      if (c > TOPK) lo = mid; else hi = mid;
    }

    // weights on kept entries (ties at cutoff kept, matching scores>=cutoff)
    float wv[32];
    float dpart = 0.f;
    int ckept = 0;
#pragma unroll
    for (int i = 0; i < 32; ++i) {
      const bool keep = (sv[i] >= cutoff);
      ckept += (int)__popcll(__ballot(keep));
      const float e = keep ? __expf(sv[i] - mx) : 0.f;
      wv[i] = e;
      dpart += e;
    }
    float denom = dpart;
#pragma unroll
    for (int off = 32; off >= 1; off >>= 1) denom += __shfl_xor(denom, off);
    const float inv_denom = 1.0f / denom;

    float e = 0.f;
    if (ckept <= 64) {
      // ballot compaction of survivors into the aliased LDS lists (ascending k)
      int base = 0;
#pragma unroll
      for (int i = 0; i < 32; ++i) {
        const unsigned long long mball = __ballot(wv[i] > 0.f);
        if (wv[i] > 0.f) {
          const int pos = base + (int)__popcll(mball & ((1ull << l) - 1ull));
          wl[pos] = wv[i];
          kl[pos] = __int_as_float(64 * i + l);
        }
        base += (int)__popcll(mball);
      }
      asm volatile("s_waitcnt lgkmcnt(0)" ::: "memory");
      // PV gather, batched x8: 8 independent V loads in flight per batch.
      // fma chain order (ascending survivor index) preserved bit-identically.
      int i = 0;
      for (; i + 8 <= ckept; i += 8) {
        float ww[8]; int kk[8];
#pragma unroll
        for (int u = 0; u < 8; ++u) { ww[u] = wl[i + u]; kk[u] = __float_as_int(kl[i + u]); }
        float vv[8];
#pragma unroll
        for (int u = 0; u < 8; ++u) vv[u] = Vh[(size_t)kk[u] * DD + l];
#pragma unroll
        for (int u = 0; u < 8; ++u) e = fmaf(ww[u], vv[u], e);
      }
      for (; i < ckept; ++i) {
        const float ww = wl[i];
        const int kk = __float_as_int(kl[i]);
        e = fmaf(ww, Vh[(size_t)kk * DD + l], e);
      }
    } else {
      // pathological-tie fallback: dense accumulation (own row only)
#pragma unroll
      for (int i = 0; i < 32; ++i) Srow[r * 2048 + 64 * i + l] = wv[i];
      asm volatile("s_waitcnt lgkmcnt(0)" ::: "memory");
      for (int k = 0; k < 2048; ++k) {
        const float ww = Srow[r * 2048 + k];
        if (ww > 0.f) e = fmaf(ww, Vh[(size_t)k * DD + l], e);
      }
    }
    outh[l] = e * inv_denom;
  }
}

extern "C" void kernel_launch(void* const* d_in, const int* in_sizes, int n_in,
                              void* d_out, int out_size, void* d_ws, size_t ws_size,
                              hipStream_t stream) {
  const float* query = (const float*)d_in[0];
  const float* key   = (const float*)d_in[1];
  const float* value = (const float*)d_in[2];
  const float* Wq    = (const float*)d_in[3];
  const float* Wk    = (const float*)d_in[4];
  float* out = (float*)d_out;

  float* Qp = (float*)d_ws;                                  // 16.8 MB
  float* Kp = Qp + (size_t)BB * HH * SS * DA;                // 16.8 MB

  proj_kernel<<<dim3(16, 64, 2), 256, 0, stream>>>(query, Wq, Qp, key, Wk, Kp);
  attn_kernel<<<dim3(BB * HH * (SS / ROWS)), 256, 0, stream>>>(Qp, Kp, value, out);
}

// Round 4
// 1183.493 us; speedup vs baseline: 1.7264x; 1.2507x over previous
//
#include <hip/hip_runtime.h>
#include <cstdint>
#include <cstddef>

#define BB 2
#define HH 16
#define SS 2048
#define DD 1024
#define DA 64
#define TOPK 32
#define ROWS 4   // q-rows per workgroup (1 per wave)

// ---------------- Projection GEMM: O = X @ W^T (OpenBLAS-sgemm-faithful) ----
// Per output element: strictly sequential FMA over k ascending, kc=384 panels
// combined as ((P0)+P1)+P2.  Tile 64x64, micro 4x4, 4 WGs/CU.
// Both projections fused into one launch via blockIdx.z.
// Output layout (both Q and K): O[((b*16+h)*2048+s)*64+da]
__global__ __launch_bounds__(256, 4) void proj_kernel(const float* __restrict__ X0,
                                                      const float* __restrict__ W0,
                                                      float* __restrict__ O0,
                                                      const float* __restrict__ X1,
                                                      const float* __restrict__ W1,
                                                      float* __restrict__ O1) {
  const float* __restrict__ X = blockIdx.z ? X1 : X0;
  const float* __restrict__ W = blockIdx.z ? W1 : W0;
  float* __restrict__ O       = blockIdx.z ? O1 : O0;

  __shared__ float Ast[16][64];
  __shared__ float Bst[16][64];
  const int tid = threadIdx.x;
  const int tx = tid & 15, ty = tid >> 4;
  const int m0 = blockIdx.y * 64, n0 = blockIdx.x * 64;

  float res[4][4], acc[4][4];
#pragma unroll
  for (int i = 0; i < 4; ++i)
#pragma unroll
    for (int j = 0; j < 4; ++j) { res[i][j] = 0.f; acc[i][j] = 0.f; }

  const int srow = tid >> 2, skg = tid & 3;   // staging: one float4 per thread
  for (int k0 = 0; k0 < 1024; k0 += 16) {
    if (k0 == 384 || k0 == 768) {   // OpenBLAS kc-panel boundary
#pragma unroll
      for (int i = 0; i < 4; ++i)
#pragma unroll
        for (int j = 0; j < 4; ++j) { res[i][j] = __fadd_rn(res[i][j], acc[i][j]); acc[i][j] = 0.f; }
    }
    {
      const float4 va = *(const float4*)(X + (size_t)(m0 + srow) * 1024 + k0 + skg * 4);
      Ast[skg * 4 + 0][srow] = va.x; Ast[skg * 4 + 1][srow] = va.y;
      Ast[skg * 4 + 2][srow] = va.z; Ast[skg * 4 + 3][srow] = va.w;
      const float4 vb = *(const float4*)(W + (size_t)(n0 + srow) * 1024 + k0 + skg * 4);
      Bst[skg * 4 + 0][srow] = vb.x; Bst[skg * 4 + 1][srow] = vb.y;
      Bst[skg * 4 + 2][srow] = vb.z; Bst[skg * 4 + 3][srow] = vb.w;
    }
    __syncthreads();
#pragma unroll
    for (int k = 0; k < 16; ++k) {
      float av[4], bv[4];
#pragma unroll
      for (int i = 0; i < 4; ++i) av[i] = Ast[k][ty * 4 + i];
#pragma unroll
      for (int j = 0; j < 4; ++j) bv[j] = Bst[k][tx * 4 + j];
#pragma unroll
      for (int i = 0; i < 4; ++i)
#pragma unroll
        for (int j = 0; j < 4; ++j) acc[i][j] = fmaf(av[i], bv[j], acc[i][j]);
    }
    __syncthreads();
  }

#pragma unroll
  for (int i = 0; i < 4; ++i) {
    const int m = m0 + ty * 4 + i;
    const int b = m >> 11, s = m & 2047;
#pragma unroll
    for (int j = 0; j < 4; ++j) {
      const int n = n0 + tx * 4 + j;
      const int h = n >> 6, da = n & 63;
      O[(((size_t)(b * 16 + h) * 2048 + s) * 64 + da)] = __fadd_rn(res[i][j], acc[i][j]);
    }
  }
}

// ---------------- Fused topk-attention (np.einsum-faithful f32 scores) ------
// Bit-identical per-(row,key) chain (SSE 4-lane, no FMA, groups of 16
// ascending, 4-blocks descending, (a0+a1)+(a2+a3), *0.125).
// WG = 256 threads (4 waves) per (bh, 4 q-rows).  LDS exactly 32768 B.
//
// Round-4: EXACT round-1 loop structure (VGPR 48, 8-waves/EU band, occ 45.6%)
// -- round-3 proved TLP beats ILP here (prefetch at VGPR=100 halved occupancy
// and lost 30%).  The one addition kept from rounds 2/3 is the bijective
// XCD-chunk swizzle, which round 3 PROVED effective (FETCH 143MB -> 33MB):
// all 512 row-blocks of one (b,h) share an XCD, so the 512KB K panel and
// 512KB V head-slice are L2-resident (~200cy) instead of L3 (~600cy).
// At ~3.7 resident waves/SIMD, per-wave duty 256cy/(256+200)cy = 56% x 3.7
// saturates the VALU issue port where round 1 (duty ~30%) starved it.
__global__ __launch_bounds__(256) void attn_kernel(const float* __restrict__ Qp,
                                                   const float* __restrict__ Kp,
                                                   const float* __restrict__ V,
                                                   float* __restrict__ out) {
  __shared__ float Srow[ROWS * 2048];   // 32 KB score block (+aliased lists)

  const int tid = threadIdx.x;
  const int w = tid >> 6, l = tid & 63;
  // bijective XCD-chunk swizzle (nwg = 16384, divisible by 8 XCDs)
  const int nwg = BB * HH * (SS / ROWS);
  const int bidx = (int)blockIdx.x;
  const int swz = (bidx & 7) * (nwg >> 3) + (bidx >> 3);
  const int bh = swz >> 9;
  const int rb = swz & 511;
  const int b = bh >> 4, h = bh & 15;
  const int r0 = rb * ROWS;

  const float* Kh = Kp + (size_t)bh * SS * DA;             // [2048][64]

  // ----- score phase: each thread handles keys tid + 256*c, c = 0..7 --------
#pragma unroll 1
  for (int c = 0; c < 8; ++c) {
    const int key = tid + c * 256;
    const float4* kp4 = (const float4*)(Kh + (size_t)key * DA);

    float acc[ROWS][4];                 // [row][sse-lane], static-indexed
#pragma unroll
    for (int r = 0; r < ROWS; ++r)
#pragma unroll
      for (int j = 0; j < 4; ++j) acc[r][j] = 0.f;

#pragma unroll
    for (int g = 0; g < 4; ++g) {       // groups of 16, ascending
      float4 kt[4];                     // one 64B line of K
#pragma unroll
      for (int i = 0; i < 4; ++i) kt[i] = kp4[g * 4 + i];
#pragma unroll
      for (int r = 0; r < ROWS; ++r) {
        // wave-uniform Q addresses -> scalar loads
        const float4* qp4 = (const float4*)(Qp + ((size_t)bh * SS + r0 + r) * DA);
        float4 q4[4];
#pragma unroll
        for (int i = 0; i < 4; ++i) q4[i] = qp4[g * 4 + i];
#pragma unroll
        for (int blk = 3; blk >= 0; --blk) {   // 4-blocks DESCENDING in group
          acc[r][0] = __fadd_rn(acc[r][0], __fmul_rn(q4[blk].x, kt[blk].x));
          acc[r][1] = __fadd_rn(acc[r][1], __fmul_rn(q4[blk].y, kt[blk].y));
          acc[r][2] = __fadd_rn(acc[r][2], __fmul_rn(q4[blk].z, kt[blk].z));
          acc[r][3] = __fadd_rn(acc[r][3], __fmul_rn(q4[blk].w, kt[blk].w));
        }
      }
    }
#pragma unroll
    for (int r = 0; r < ROWS; ++r) {
      const float s = __fadd_rn(__fadd_rn(acc[r][0], acc[r][1]),
                                __fadd_rn(acc[r][2], acc[r][3]));
      Srow[r * 2048 + key] = s * 0.125f;
    }
  }
  __syncthreads();

  const float* Vh = V + (size_t)b * SS * DD + h * DA;
  float* outh = out + ((size_t)(b * SS + r0 + w)) * DD + h * DA;

  // ----- per-wave: one row (r = w): exact top-32, softmax, sparse PV --------
  {
    const int r = w;
    float sv[32];
#pragma unroll
    for (int i = 0; i < 32; ++i) sv[i] = Srow[r * 2048 + 64 * i + l];
    // From here on, this wave's Srow slice is dead: reuse the first 128
    // floats of it as the survivor (weight,key) lists.
    float* wl = &Srow[r * 2048];        // [0..63]  survivor weights
    float* kl = &Srow[r * 2048 + 64];   // [64..127] survivor keys (bit-punned)

    float mx = sv[0], mn = sv[0];
#pragma unroll
    for (int i = 1; i < 32; ++i) { mx = fmaxf(mx, sv[i]); mn = fminf(mn, sv[i]); }
#pragma unroll
    for (int off = 32; off >= 1; off >>= 1) {
      mx = fmaxf(mx, __shfl_xor(mx, off));
      mn = fminf(mn, __shfl_xor(mn, off));
    }

    // bisection for the exact 32nd-largest score value.
    float lo = mn, hi = mx + 1.0f;
    float cutoff = mn;
    for (int it = 0; ; ++it) {
      const float mid = 0.5f * (lo + hi);
      if (it >= 64 || !(mid > lo && mid < hi)) { cutoff = lo; break; }
      int c = 0;
#pragma unroll
      for (int i = 0; i < 32; ++i)
        c += (int)__popcll(__ballot(sv[i] >= mid));
      if (c == TOPK) {
        float cm = 3.0e38f;
#pragma unroll
        for (int i = 0; i < 32; ++i) if (sv[i] >= mid) cm = fminf(cm, sv[i]);
#pragma unroll
        for (int off = 32; off >= 1; off >>= 1) cm = fminf(cm, __shfl_xor(cm, off));
        cutoff = cm;
        break;
      }
      if (c > TOPK) lo = mid; else hi = mid;
    }

    // weights on kept entries (ties at cutoff kept, matching scores>=cutoff)
    float wv[32];
    float dpart = 0.f;
    int ckept = 0;
#pragma unroll
    for (int i = 0; i < 32; ++i) {
      const bool keep = (sv[i] >= cutoff);
      ckept += (int)__popcll(__ballot(keep));
      const float e = keep ? __expf(sv[i] - mx) : 0.f;
      wv[i] = e;
      dpart += e;
    }
    float denom = dpart;
#pragma unroll
    for (int off = 32; off >= 1; off >>= 1) denom += __shfl_xor(denom, off);
    const float inv_denom = 1.0f / denom;

    float e = 0.f;
    if (ckept <= 64) {
      // ballot compaction of survivors into the aliased LDS lists (ascending k)
      int base = 0;
#pragma unroll
      for (int i = 0; i < 32; ++i) {
        const unsigned long long mball = __ballot(wv[i] > 0.f);
        if (wv[i] > 0.f) {
          const int pos = base + (int)__popcll(mball & ((1ull << l) - 1ull));
          wl[pos] = wv[i];
          kl[pos] = __int_as_float(64 * i + l);
        }
        base += (int)__popcll(mball);
      }
      asm volatile("s_waitcnt lgkmcnt(0)" ::: "memory");
      // PV gather, batched x8: 8 independent V loads in flight per batch.
      // fma chain order (ascending survivor index) preserved bit-identically.
      int i = 0;
      for (; i + 8 <= ckept; i += 8) {
        float ww[8]; int kk[8];
#pragma unroll
        for (int u = 0; u < 8; ++u) { ww[u] = wl[i + u]; kk[u] = __float_as_int(kl[i + u]); }
        float vv[8];
#pragma unroll
        for (int u = 0; u < 8; ++u) vv[u] = Vh[(size_t)kk[u] * DD + l];
#pragma unroll
        for (int u = 0; u < 8; ++u) e = fmaf(ww[u], vv[u], e);
      }
      for (; i < ckept; ++i) {
        const float ww = wl[i];
        const int kk = __float_as_int(kl[i]);
        e = fmaf(ww, Vh[(size_t)kk * DD + l], e);
      }
    } else {
      // pathological-tie fallback: dense accumulation (own row only)
#pragma unroll
      for (int i = 0; i < 32; ++i) Srow[r * 2048 + 64 * i + l] = wv[i];
      asm volatile("s_waitcnt lgkmcnt(0)" ::: "memory");
      for (int k = 0; k < 2048; ++k) {
        const float ww = Srow[r * 2048 + k];
        if (ww > 0.f) e = fmaf(ww, Vh[(size_t)k * DD + l], e);
      }
    }
    outh[l] = e * inv_denom;
  }
}

extern "C" void kernel_launch(void* const* d_in, const int* in_sizes, int n_in,
                              void* d_out, int out_size, void* d_ws, size_t ws_size,
                              hipStream_t stream) {
  const float* query = (const float*)d_in[0];
  const float* key   = (const float*)d_in[1];
  const float* value = (const float*)d_in[2];
  const float* Wq    = (const float*)d_in[3];
  const float* Wk    = (const float*)d_in[4];
  float* out = (float*)d_out;

  float* Qp = (float*)d_ws;                                  // 16.8 MB
  float* Kp = Qp + (size_t)BB * HH * SS * DA;                // 16.8 MB

  proj_kernel<<<dim3(16, 64, 2), 256, 0, stream>>>(query, Wq, Qp, key, Wk, Kp);
  attn_kernel<<<dim3(BB * HH * (SS / ROWS)), 256, 0, stream>>>(Qp, Kp, value, out);
}